// Round 8
// baseline (762.175 us; speedup 1.0000x reference)
//
#include <hip/hip_runtime.h>
#include <hip/hip_bf16.h>
#include <stdint.h>

typedef unsigned short u16;
typedef short s16x8 __attribute__((ext_vector_type(8)));
typedef float f32x4 __attribute__((ext_vector_type(4)));
typedef unsigned short u16x4 __attribute__((ext_vector_type(4)));
typedef unsigned short u16x8 __attribute__((ext_vector_type(8)));

#define B_ 8
#define T_ 1024
#define C_ 512
#define H_ 8
#define M_ (B_*T_)   // 8192

__device__ __forceinline__ u16 f2bf(float f) {
  unsigned u = __builtin_bit_cast(unsigned, f);
  u += 0x7FFFu + ((u >> 16) & 1u);
  return (u16)(u >> 16);
}

__device__ __forceinline__ f32x4 mfma16(s16x8 a, s16x8 b, f32x4 c) {
  return __builtin_amdgcn_mfma_f32_16x16x32_bf16(a, b, c, 0, 0, 0);
}

__device__ __forceinline__ void glds16(const void* g, void* l) {
  __builtin_amdgcn_global_load_lds(
      (__attribute__((address_space(1))) const uint32_t*)g,
      (__attribute__((address_space(3))) uint32_t*)l, 16, 0, 0);
}

// ---------------------------------------------------------------- x -> bf16
__global__ void cvt_x(const float* __restrict__ src, u16* __restrict__ dst, int n8) {
  int i = blockIdx.x * blockDim.x + threadIdx.x;
  if (i < n8) {
    float4 a = ((const float4*)src)[2*i];
    float4 b = ((const float4*)src)[2*i + 1];
    u16x8 o;
    o[0]=f2bf(a.x); o[1]=f2bf(a.y); o[2]=f2bf(a.z); o[3]=f2bf(a.w);
    o[4]=f2bf(b.x); o[5]=f2bf(b.y); o[6]=f2bf(b.z); o[7]=f2bf(b.w);
    ((u16x8*)dst)[i] = o;
  }
}

// -------------------------------------------- f32 [R][Cc] -> bf16 [Cc][R]
__global__ void transpose_f32_to_bf16(const float* __restrict__ src, u16* __restrict__ dst,
                                      int R, int Cc, long sstride, long dstride) {
  int nTc = Cc >> 5;
  int tr = (blockIdx.x / nTc) << 5;
  int tc = (blockIdx.x % nTc) << 5;
  src += (long)blockIdx.y * sstride;
  dst += (long)blockIdx.y * dstride;
  __shared__ float tile[32][33];
  int tx = threadIdx.x, ty = threadIdx.y;  // (32, 8)
  #pragma unroll
  for (int i = 0; i < 4; ++i) {
    int r = ty + i*8;
    tile[r][tx] = src[(long)(tr + r)*Cc + tc + tx];
  }
  __syncthreads();
  #pragma unroll
  for (int i = 0; i < 4; ++i) {
    int r = ty + i*8;
    dst[(long)(tc + r)*R + tr + tx] = f2bf(tile[tx][r]);
  }
}

// ------------------------------------------------------------ staging macro
// 128x64 bf16 tile (16KB), linear LDS dest, inverse-swizzled global source.
#define STAGE_TILE(SRC, STRIDE, LDS)                                        \
  _Pragma("unroll")                                                         \
  for (int r_ = 0; r_ < 4; ++r_) {                                          \
    int o_ = r_*4096 + tid*16;                                              \
    int row_ = o_ >> 7, cb_ = o_ & 127;                                     \
    int cbs_ = cb_ ^ ((row_ & 7) << 4);                                     \
    glds16((SRC) + (size_t)row_*(STRIDE) + kofs + (cbs_ >> 1),              \
           (char*)(LDS) + r_*4096 + ((tid >> 6) << 10));                    \
  }

// ---------------------------------------------------------------- QKV GEMM
// A = xbf [8192,512]; B = wt[(p*8+h)][512 d][512 c] (pre-transposed).
// Group of g heads starting at h0: buffers hold hh = h-h0 in [0,g).
// p=0: Q[hh][m][d]; p=1: K[hh][m][d]; p=2: V^T[hh][b][d][t].
__global__ __launch_bounds__(256, 2) void gemm_qkv(
    const u16* __restrict__ xbf, const u16* __restrict__ wt,
    const float* __restrict__ bq, const float* __restrict__ bk, const float* __restrict__ bv,
    u16* __restrict__ qO, u16* __restrict__ kO, u16* __restrict__ vT,
    int h0, int lg)
{
  __shared__ u16 As[128*64];
  __shared__ u16 Bs[128*64];
  const int tid = threadIdx.x;
  const int lane = tid & 63, w = tid >> 6;
  const int wm = w >> 1, wn = w & 1;
  const int l15 = lane & 15, l4 = lane >> 4;
  const int by = blockIdx.y;
  const int p = by >> lg;               // 0,1,2
  const int hh = by & ((1 << lg) - 1);  // head within group
  const int h = h0 + hh;                // actual head
  const int ph = p*8 + h;
  const int mt = blockIdx.x >> 2, nt = blockIdx.x & 3;
  const int m0 = mt * 128, n0 = nt * 128;

  const u16* aSrc = xbf + (size_t)m0 * 512;
  const u16* bSrc = wt + ((size_t)ph * 512 + n0) * 512;

  f32x4 acc[4][4];
  #pragma unroll
  for (int i = 0; i < 4; ++i)
    #pragma unroll
    for (int j = 0; j < 4; ++j) acc[i][j] = f32x4{0.f,0.f,0.f,0.f};

  for (int kt = 0; kt < 8; ++kt) {
    const int kofs = kt * 64;
    STAGE_TILE(aSrc, 512, As);
    STAGE_TILE(bSrc, 512, Bs);
    __syncthreads();
    #pragma unroll
    for (int kk = 0; kk < 2; ++kk) {
      s16x8 af[4], bfr[4];
      #pragma unroll
      for (int i = 0; i < 4; ++i) {
        int rowA = wm*64 + i*16 + l15;
        af[i] = *(const s16x8*)((const char*)As + rowA*128 + ((kk*64 + l4*16) ^ ((rowA & 7) << 4)));
        int rowB = wn*64 + i*16 + l15;
        bfr[i] = *(const s16x8*)((const char*)Bs + rowB*128 + ((kk*64 + l4*16) ^ ((rowB & 7) << 4)));
      }
      #pragma unroll
      for (int i = 0; i < 4; ++i)
        #pragma unroll
        for (int j = 0; j < 4; ++j)
          acc[i][j] = mfma16(af[i], bfr[j], acc[i][j]);
    }
    __syncthreads();
  }

  const int dBase = n0 + wn*64;
  const int mBase = m0 + wm*64;
  if (p < 2) {
    const float* bias = (p == 0 ? bq : bk) + h*512;
    u16* outp = (p == 0 ? qO : kO) + (size_t)hh * M_ * 512;
    #pragma unroll
    for (int j = 0; j < 4; ++j) {
      int d = dBase + j*16 + l15;
      float bvs = bias[d];
      #pragma unroll
      for (int i = 0; i < 4; ++i) {
        int m = mBase + i*16 + l4*4;
        #pragma unroll
        for (int r = 0; r < 4; ++r)
          outp[(size_t)(m + r)*512 + d] = f2bf(acc[i][j][r] + bvs);
      }
    }
  } else {
    const float* bias = bv + h*512;
    #pragma unroll
    for (int j = 0; j < 4; ++j) {
      int d = dBase + j*16 + l15;
      float bvs = bias[d];
      #pragma unroll
      for (int i = 0; i < 4; ++i) {
        int m = mBase + i*16 + l4*4;
        int b_ = m >> 10, t0_ = m & 1023;
        u16x4 pk;
        #pragma unroll
        for (int r = 0; r < 4; ++r) pk[r] = f2bf(acc[i][j][r] + bvs);
        *(u16x4*)(vT + (((size_t)(hh*B_ + b_)*512 + d)*1024 + t0_)) = pk;
      }
    }
  }
}

// ------------------------------------------------------------- attention
// Flash loop, DOUBLE-BUFFERED K/V tiles (KVB=32), one barrier per iter:
// stage(t+1) issued async BEFORE compute(t); end-of-iter __syncthreads
// drains vmcnt after loads had the whole compute phase to land (T3-lite).
// K tile: [32 s][512 d] bf16, glds16, rows 1024B, XOR ((row&7)<<4) both sides.
// V tile: [512 d][32 s] bf16 packed 64B rows, glds16, XOR bits4-5 keyed on
//   (d>>1)&3 (key bits disjoint from XORed bits -> clean involution); read
//   slot walk {0,4,1,5,2,6,3,7} = conflict-minimum.
// Swapped QK^T: S^T = mfma(K, Q); unnormalized exp2 softmax + rowsum L;
// fused /L + per-head LayerNorm epilogue.
__global__ __launch_bounds__(256, 1) void attn(
    const u16* __restrict__ qB, const u16* __restrict__ kB, const u16* __restrict__ vT,
    const float* __restrict__ lng, const float* __restrict__ lnb,
    u16* __restrict__ zO, int h0)
{
  __shared__ u16 Ks[2][32*512];   // 2 x 32 KB
  __shared__ u16 Vs[2][512*32];   // 2 x 32 KB
  __shared__ u16 Pl[4][512];      // 4 KB per-wave P (swizzled)
  const int tid = threadIdx.x;
  const int lane = tid & 63, w = tid >> 6;
  const int l15 = lane & 15, l4 = lane >> 4;

  // XCD swizzle: 16 consecutive-slot blocks of one (hg,b) land on one XCD.
  const int Dd = blockIdx.x;
  const int xcd = Dd & 7, slot = Dd >> 3;
  const int gg = xcd + 8*(slot >> 4);    // (hg,b) pair
  const int qt = slot & 15;
  const int hg = gg >> 3, b = gg & 7;
  const int h = h0 + hg;
  const int t0 = qt*64 + w*16;
  const size_t hb = (size_t)hg*B_ + b;

  const u16* qP = qB + (hb*1024 + t0 + l15)*512 + l4*8;
  s16x8 qf[16];
  #pragma unroll
  for (int ks = 0; ks < 16; ++ks) qf[ks] = *(const s16x8*)(qP + ks*32);

  f32x4 z[32];
  #pragma unroll
  for (int df = 0; df < 32; ++df) z[df] = f32x4{0.f,0.f,0.f,0.f};
  float L = 0.f;
  const float c1 = 0.06376390696f;   // (1/sqrt(512)) * log2(e)

  const u16* kBase = kB + hb*1024*512;   // K[t][d], 1024B rows
  const u16* vBase = vT + hb*512*1024;   // V^T[d][t], 2048B rows
  char* myP = (char*)&Pl[w][0];
  const int swz = (l15 & 3) << 4;
  const int kswz = (l15 & 7) << 4;

  auto stageK = [&](int buf, int s0) {
    #pragma unroll
    for (int it = 0; it < 8; ++it) {
      int o = it*4096 + tid*16;
      int row = o >> 10, cb = o & 1023;
      int cbs = cb ^ ((row & 7) << 4);
      glds16(kBase + (size_t)(s0 + row)*512 + (cbs >> 1),
             (char*)Ks[buf] + it*4096 + ((tid >> 6) << 10));
    }
  };
  auto stageV = [&](int buf, int s0) {
    #pragma unroll
    for (int it = 0; it < 8; ++it) {
      int F = it*4096 + tid*16;                       // flat LDS byte offset
      int d = F >> 6;                                 // V row (0..511)
      int cl = (F & 63) ^ (((d >> 1) & 3) << 4);      // logical col bytes
      glds16(vBase + (size_t)d*1024 + s0 + (cl >> 1),
             (char*)Vs[buf] + it*4096 + ((tid >> 6) << 10));
    }
  };

  stageK(0, 0);
  stageV(0, 0);
  __syncthreads();

  for (int itr = 0; itr < 32; ++itr) {
    const int s0 = itr << 5;
    const int cur = itr & 1;
    if (itr < 31) { stageK(cur ^ 1, s0 + 32); stageV(cur ^ 1, s0 + 32); }

    // ---- QK^T from LDS
    f32x4 sf0 = f32x4{0.f,0.f,0.f,0.f};
    f32x4 sf1 = f32x4{0.f,0.f,0.f,0.f};
    const char* ksb = (const char*)Ks[cur];
    #pragma unroll
    for (int ks = 0; ks < 16; ++ks) {
      int col = (ks*64 + l4*16) ^ kswz;
      s16x8 k0 = *(const s16x8*)(ksb + l15*1024 + col);
      s16x8 k1 = *(const s16x8*)(ksb + (16 + l15)*1024 + col);
      sf0 = mfma16(k0, qf[ks], sf0);
      sf1 = mfma16(k1, qf[ks], sf1);
    }
    u16x4 p0, p1;
    #pragma unroll
    for (int r = 0; r < 4; ++r) {
      float e0 = exp2f(sf0[r] * c1);
      float e1 = exp2f(sf1[r] * c1);
      L += e0 + e1;
      p0[r] = f2bf(e0);
      p1[r] = f2bf(e1);
    }
    // P round-trip is wave-private (no barrier needed)
    *(u16x4*)(myP + l15*64 + (( l4*8      ) ^ swz)) = p0;
    *(u16x4*)(myP + l15*64 + ((32 + l4*8  ) ^ swz)) = p1;
    s16x8 pb = *(const s16x8*)(myP + l15*64 + ((l4*16) ^ swz));

    // ---- PV from LDS (swizzled packed rows)
    const char* vsb = (const char*)Vs[cur];
    #pragma unroll
    for (int df = 0; df < 32; ++df) {
      int d = df*16 + l15;
      int off = (d << 6) + ((l4 << 4) ^ (((d >> 1) & 3) << 4));
      s16x8 va = *(const s16x8*)(vsb + off);
      z[df] = mfma16(va, pb, z[df]);
    }
    __syncthreads();   // next-tile stage drained; cur safe to restage next iter
  }

  // rowsum over the four lane-groups
  L += __shfl_xor(L, 16);
  L += __shfl_xor(L, 32);
  float inv = 1.f / L;

  float s1 = 0.f, s2 = 0.f;
  #pragma unroll
  for (int df = 0; df < 32; ++df)
    #pragma unroll
    for (int r = 0; r < 4; ++r) {
      float v = z[df][r] * inv;
      z[df][r] = v;
      s1 += v; s2 += v*v;
    }
  s1 += __shfl_xor(s1, 16); s1 += __shfl_xor(s1, 32);
  s2 += __shfl_xor(s2, 16); s2 += __shfl_xor(s2, 32);
  const float mean = s1 * (1.f/512.f);
  const float var  = s2 * (1.f/512.f) - mean*mean;
  const float rstd = rsqrtf(var + 1e-5f);

  const float* gp = lng + h*512;
  const float* bp = lnb + h*512;
  u16* zp = zO + ((size_t)(b*1024 + t0 + l15))*4096 + h*512;
  #pragma unroll
  for (int df = 0; df < 32; ++df) {
    int d0 = df*16 + l4*4;
    float4 gv  = *(const float4*)(gp + d0);
    float4 bbv = *(const float4*)(bp + d0);
    u16x4 pk;
    pk[0] = f2bf((z[df][0]-mean)*rstd*gv.x + bbv.x);
    pk[1] = f2bf((z[df][1]-mean)*rstd*gv.y + bbv.y);
    pk[2] = f2bf((z[df][2]-mean)*rstd*gv.z + bbv.z);
    pk[3] = f2bf((z[df][3]-mean)*rstd*gv.w + bbv.w);
    *(u16x4*)(zp + d0) = pk;
  }
}

// ---------------------------------------------------------------- final FC
// out = zc @ Wf + bf + x ;  A = zb [8192,4096], B = wft [512][4096]
__global__ __launch_bounds__(256, 2) void gemm_fc(
    const u16* __restrict__ zb, const u16* __restrict__ wft,
    const float* __restrict__ bf_, const float* __restrict__ x,
    float* __restrict__ out)
{
  __shared__ u16 As[128*64];
  __shared__ u16 Bs[128*64];
  const int tid = threadIdx.x;
  const int lane = tid & 63, w = tid >> 6;
  const int wm = w >> 1, wn = w & 1;
  const int l15 = lane & 15, l4 = lane >> 4;
  const int mt = blockIdx.x >> 2, nt = blockIdx.x & 3;
  const int m0 = mt * 128, n0 = nt * 128;

  const u16* aSrc = zb + (size_t)m0 * 4096;
  const u16* bSrc = wft + (size_t)n0 * 4096;

  f32x4 acc[4][4];
  #pragma unroll
  for (int i = 0; i < 4; ++i)
    #pragma unroll
    for (int j = 0; j < 4; ++j) acc[i][j] = f32x4{0.f,0.f,0.f,0.f};

  for (int kt = 0; kt < 64; ++kt) {
    const int kofs = kt * 64;
    STAGE_TILE(aSrc, 4096, As);
    STAGE_TILE(bSrc, 4096, Bs);
    __syncthreads();
    #pragma unroll
    for (int kk = 0; kk < 2; ++kk) {
      s16x8 af[4], bfr[4];
      #pragma unroll
      for (int i = 0; i < 4; ++i) {
        int rowA = wm*64 + i*16 + l15;
        af[i] = *(const s16x8*)((const char*)As + rowA*128 + ((kk*64 + l4*16) ^ ((rowA & 7) << 4)));
        int rowB = wn*64 + i*16 + l15;
        bfr[i] = *(const s16x8*)((const char*)Bs + rowB*128 + ((kk*64 + l4*16) ^ ((rowB & 7) << 4)));
      }
      #pragma unroll
      for (int i = 0; i < 4; ++i)
        #pragma unroll
        for (int j = 0; j < 4; ++j)
          acc[i][j] = mfma16(af[i], bfr[j], acc[i][j]);
    }
    __syncthreads();
  }

  const int dBase = n0 + wn*64;
  const int mBase = m0 + wm*64;
  #pragma unroll
  for (int j = 0; j < 4; ++j) {
    int d = dBase + j*16 + l15;
    float bvs = bf_[d];
    #pragma unroll
    for (int i = 0; i < 4; ++i) {
      int m = mBase + i*16 + l4*4;
      #pragma unroll
      for (int r = 0; r < 4; ++r) {
        size_t idx = (size_t)(m + r)*512 + d;
        out[idx] = acc[i][j][r] + bvs + x[idx];
      }
    }
  }
}

// ------------------------------------------------------------------ launch
extern "C" void kernel_launch(void* const* d_in, const int* in_sizes, int n_in,
                              void* d_out, int out_size, void* d_ws, size_t ws_size,
                              hipStream_t stream) {
  const float* x   = (const float*)d_in[0];
  const float* Wq  = (const float*)d_in[1];
  const float* bq  = (const float*)d_in[2];
  const float* Wk  = (const float*)d_in[3];
  const float* bk  = (const float*)d_in[4];
  const float* Wv  = (const float*)d_in[5];
  const float* bv  = (const float*)d_in[6];
  const float* lng = (const float*)d_in[7];
  const float* lnb = (const float*)d_in[8];
  const float* Wf  = (const float*)d_in[9];
  const float* bf_ = (const float*)d_in[10];
  float* out = (float*)d_out;

  // ws layout (bytes):
  //   xbf  [8192][512] bf16                  @ 0          (8,388,608)
  //   wt   [24][512][512] bf16               @ 8,388,608  (12,582,912)
  //   wft  [512][4096] bf16                  @ 20,971,520 (4,194,304)
  //   zb   [8192][4096] bf16                 @ 25,165,824 (67,108,864)
  //   q,k,v: g heads each, 8,388,608*g each  @ 92,274,688
  // peak = 92,274,688 + 3*g*8,388,608 : g=8 -> 280 MiB, 4 -> 184, 2 -> 136, 1 -> 112.
  char* ws = (char*)d_ws;
  u16* xbf = (u16*)(ws);
  u16* wt  = (u16*)(ws + 8388608);
  u16* wft = (u16*)(ws + 20971520);
  u16* zb  = (u16*)(ws + 25165824);

  const size_t headB = 8388608;  // one head of q/k/v in bytes
  const size_t base  = 92274688;
  int g, lg;
  if      (ws_size >= base + 24*headB) { g = 8; lg = 3; }
  else if (ws_size >= base + 12*headB) { g = 4; lg = 2; }
  else if (ws_size >= base +  6*headB) { g = 2; lg = 1; }
  else                                 { g = 1; lg = 0; }

  u16* qb = (u16*)(ws + base);
  u16* kb = (u16*)(ws + base + (size_t)g*headB);
  u16* vt = (u16*)(ws + base + (size_t)2*g*headB);

  cvt_x<<<2048, 256, 0, stream>>>(x, xbf, 524288);
  dim3 tb(32, 8);
  transpose_f32_to_bf16<<<dim3(256, 8), tb, 0, stream>>>(Wq, wt,             512, 512, 262144, 262144);
  transpose_f32_to_bf16<<<dim3(256, 8), tb, 0, stream>>>(Wk, wt +  8*262144, 512, 512, 262144, 262144);
  transpose_f32_to_bf16<<<dim3(256, 8), tb, 0, stream>>>(Wv, wt + 16*262144, 512, 512, 262144, 262144);
  transpose_f32_to_bf16<<<dim3(2048, 1), tb, 0, stream>>>(Wf, wft, 4096, 512, 0, 0);

  for (int h0 = 0; h0 < H_; h0 += g) {
    gemm_qkv<<<dim3(256, 3*g), 256, 0, stream>>>(xbf, wt, bq, bk, bv, qb, kb, vt, h0, lg);
    attn<<<dim3(128*g), 256, 0, stream>>>(qb, kb, vt, lng, lnb, zb, h0);
  }
  gemm_fc<<<256, 256, 0, stream>>>(zb, wft, bf_, x, out);
}

// Round 13
// 556.224 us; speedup vs baseline: 1.3703x; 1.3703x over previous
//
#include <hip/hip_runtime.h>
#include <hip/hip_bf16.h>
#include <stdint.h>

typedef unsigned short u16;
typedef short s16x8 __attribute__((ext_vector_type(8)));
typedef float f32x4 __attribute__((ext_vector_type(4)));
typedef unsigned short u16x4 __attribute__((ext_vector_type(4)));
typedef unsigned short u16x8 __attribute__((ext_vector_type(8)));

#define B_ 8
#define T_ 1024
#define C_ 512
#define H_ 8
#define M_ (B_*T_)   // 8192

__device__ __forceinline__ u16 f2bf(float f) {
  unsigned u = __builtin_bit_cast(unsigned, f);
  u += 0x7FFFu + ((u >> 16) & 1u);
  return (u16)(u >> 16);
}

__device__ __forceinline__ f32x4 mfma16(s16x8 a, s16x8 b, f32x4 c) {
  return __builtin_amdgcn_mfma_f32_16x16x32_bf16(a, b, c, 0, 0, 0);
}

__device__ __forceinline__ void glds16(const void* g, void* l) {
  __builtin_amdgcn_global_load_lds(
      (__attribute__((address_space(1))) const uint32_t*)g,
      (__attribute__((address_space(3))) uint32_t*)l, 16, 0, 0);
}

// ---------------------------------------------------------------- x -> bf16
__global__ void cvt_x(const float* __restrict__ src, u16* __restrict__ dst, int n8) {
  int i = blockIdx.x * blockDim.x + threadIdx.x;
  if (i < n8) {
    float4 a = ((const float4*)src)[2*i];
    float4 b = ((const float4*)src)[2*i + 1];
    u16x8 o;
    o[0]=f2bf(a.x); o[1]=f2bf(a.y); o[2]=f2bf(a.z); o[3]=f2bf(a.w);
    o[4]=f2bf(b.x); o[5]=f2bf(b.y); o[6]=f2bf(b.z); o[7]=f2bf(b.w);
    ((u16x8*)dst)[i] = o;
  }
}

// -------------------------------------------- f32 [R][Cc] -> bf16 [Cc][R]
__global__ void transpose_f32_to_bf16(const float* __restrict__ src, u16* __restrict__ dst,
                                      int R, int Cc, long sstride, long dstride) {
  int nTc = Cc >> 5;
  int tr = (blockIdx.x / nTc) << 5;
  int tc = (blockIdx.x % nTc) << 5;
  src += (long)blockIdx.y * sstride;
  dst += (long)blockIdx.y * dstride;
  __shared__ float tile[32][33];
  int tx = threadIdx.x, ty = threadIdx.y;  // (32, 8)
  #pragma unroll
  for (int i = 0; i < 4; ++i) {
    int r = ty + i*8;
    tile[r][tx] = src[(long)(tr + r)*Cc + tc + tx];
  }
  __syncthreads();
  #pragma unroll
  for (int i = 0; i < 4; ++i) {
    int r = ty + i*8;
    dst[(long)(tc + r)*R + tr + tx] = f2bf(tile[tx][r]);
  }
}

// ------------------------------------------------------------ staging macro
// 128x64 bf16 tile (16KB), linear LDS dest, inverse-swizzled global source.
#define STAGE_TILE(SRC, STRIDE, LDS)                                        \
  _Pragma("unroll")                                                         \
  for (int r_ = 0; r_ < 4; ++r_) {                                          \
    int o_ = r_*4096 + tid*16;                                              \
    int row_ = o_ >> 7, cb_ = o_ & 127;                                     \
    int cbs_ = cb_ ^ ((row_ & 7) << 4);                                     \
    glds16((SRC) + (size_t)row_*(STRIDE) + kofs + (cbs_ >> 1),              \
           (char*)(LDS) + r_*4096 + ((tid >> 6) << 10));                    \
  }

// ---------------------------------------------------------------- QKV GEMM
// A = xbf [8192,512]; B = wt[(p*8+h)][512 d][512 c] (pre-transposed).
// Group of g heads starting at h0: buffers hold hh = h-h0 in [0,g).
// p=0: Q[hh][m][d]; p=1: K[hh][m][d]; p=2: V^T[hh][b][d][t].
__global__ __launch_bounds__(256, 2) void gemm_qkv(
    const u16* __restrict__ xbf, const u16* __restrict__ wt,
    const float* __restrict__ bq, const float* __restrict__ bk, const float* __restrict__ bv,
    u16* __restrict__ qO, u16* __restrict__ kO, u16* __restrict__ vT,
    int h0, int lg)
{
  __shared__ u16 As[128*64];
  __shared__ u16 Bs[128*64];
  const int tid = threadIdx.x;
  const int lane = tid & 63, w = tid >> 6;
  const int wm = w >> 1, wn = w & 1;
  const int l15 = lane & 15, l4 = lane >> 4;
  const int by = blockIdx.y;
  const int p = by >> lg;               // 0,1,2
  const int hh = by & ((1 << lg) - 1);  // head within group
  const int h = h0 + hh;                // actual head
  const int ph = p*8 + h;
  const int mt = blockIdx.x >> 2, nt = blockIdx.x & 3;
  const int m0 = mt * 128, n0 = nt * 128;

  const u16* aSrc = xbf + (size_t)m0 * 512;
  const u16* bSrc = wt + ((size_t)ph * 512 + n0) * 512;

  f32x4 acc[4][4];
  #pragma unroll
  for (int i = 0; i < 4; ++i)
    #pragma unroll
    for (int j = 0; j < 4; ++j) acc[i][j] = f32x4{0.f,0.f,0.f,0.f};

  for (int kt = 0; kt < 8; ++kt) {
    const int kofs = kt * 64;
    STAGE_TILE(aSrc, 512, As);
    STAGE_TILE(bSrc, 512, Bs);
    __syncthreads();
    #pragma unroll
    for (int kk = 0; kk < 2; ++kk) {
      s16x8 af[4], bfr[4];
      #pragma unroll
      for (int i = 0; i < 4; ++i) {
        int rowA = wm*64 + i*16 + l15;
        af[i] = *(const s16x8*)((const char*)As + rowA*128 + ((kk*64 + l4*16) ^ ((rowA & 7) << 4)));
        int rowB = wn*64 + i*16 + l15;
        bfr[i] = *(const s16x8*)((const char*)Bs + rowB*128 + ((kk*64 + l4*16) ^ ((rowB & 7) << 4)));
      }
      #pragma unroll
      for (int i = 0; i < 4; ++i)
        #pragma unroll
        for (int j = 0; j < 4; ++j)
          acc[i][j] = mfma16(af[i], bfr[j], acc[i][j]);
    }
    __syncthreads();
  }

  const int dBase = n0 + wn*64;
  const int mBase = m0 + wm*64;
  if (p < 2) {
    const float* bias = (p == 0 ? bq : bk) + h*512;
    u16* outp = (p == 0 ? qO : kO) + (size_t)hh * M_ * 512;
    #pragma unroll
    for (int j = 0; j < 4; ++j) {
      int d = dBase + j*16 + l15;
      float bvs = bias[d];
      #pragma unroll
      for (int i = 0; i < 4; ++i) {
        int m = mBase + i*16 + l4*4;
        #pragma unroll
        for (int r = 0; r < 4; ++r)
          outp[(size_t)(m + r)*512 + d] = f2bf(acc[i][j][r] + bvs);
      }
    }
  } else {
    const float* bias = bv + h*512;
    #pragma unroll
    for (int j = 0; j < 4; ++j) {
      int d = dBase + j*16 + l15;
      float bvs = bias[d];
      #pragma unroll
      for (int i = 0; i < 4; ++i) {
        int m = mBase + i*16 + l4*4;
        int b_ = m >> 10, t0_ = m & 1023;
        u16x4 pk;
        #pragma unroll
        for (int r = 0; r < 4; ++r) pk[r] = f2bf(acc[i][j][r] + bvs);
        *(u16x4*)(vT + (((size_t)(hh*B_ + b_)*512 + d)*1024 + t0_)) = pk;
      }
    }
  }
}

// ------------------------------------------------------------- attention
// 8-WAVE (512-thread) flash loop, double-buffered K/V tiles (KVB=32), one
// barrier per iter. 8 waves x 16 t-rows = 128 rows/block; VGPR ~196 -> 2
// waves/SIMD (8 waves/CU) WITH the double-buffer pipeline (R6 occupancy +
// R8 pipeline). Stage(t+1) issued before compute(t); end barrier drains.
// K tile: [32 s][512 d], glds16, XOR ((row&7)<<4) both sides.
// V tile: [512 d][32 s] 64B rows, glds16, XOR bits4-5 keyed on (d>>1)&3.
// Swapped QK^T; unnormalized exp2 softmax + rowsum L; fused LN epilogue.
__global__ __launch_bounds__(512, 1) void attn(
    const u16* __restrict__ qB, const u16* __restrict__ kB, const u16* __restrict__ vT,
    const float* __restrict__ lng, const float* __restrict__ lnb,
    u16* __restrict__ zO, int h0)
{
  __shared__ u16 Ks[2][32*512];   // 2 x 32 KB
  __shared__ u16 Vs[2][512*32];   // 2 x 32 KB
  __shared__ u16 Pl[8][512];      // 8 KB per-wave P (swizzled)
  const int tid = threadIdx.x;
  const int lane = tid & 63, w = tid >> 6;       // w in 0..7
  const int l15 = lane & 15, l4 = lane >> 4;

  // XCD swizzle: 8 consecutive-slot blocks of one (hg,b) land on one XCD.
  const int Dd = blockIdx.x;
  const int xcd = Dd & 7, slot = Dd >> 3;
  const int gg = xcd + 8*(slot >> 3);    // (hg,b) pair
  const int qt = slot & 7;               // 8 q-tiles of 128 rows
  const int hg = gg >> 3, b = gg & 7;
  const int h = h0 + hg;
  const int t0 = qt*128 + w*16;
  const size_t hb = (size_t)hg*B_ + b;

  const u16* qP = qB + (hb*1024 + t0 + l15)*512 + l4*8;
  s16x8 qf[16];
  #pragma unroll
  for (int ks = 0; ks < 16; ++ks) qf[ks] = *(const s16x8*)(qP + ks*32);

  f32x4 z[32];
  #pragma unroll
  for (int df = 0; df < 32; ++df) z[df] = f32x4{0.f,0.f,0.f,0.f};
  float L = 0.f;
  const float c1 = 0.06376390696f;   // (1/sqrt(512)) * log2(e)

  const u16* kBase = kB + hb*1024*512;   // K[t][d], 1024B rows
  const u16* vBase = vT + hb*512*1024;   // V^T[d][t], 2048B rows
  char* myP = (char*)&Pl[w][0];
  const int swz = (l15 & 3) << 4;
  const int kswz = (l15 & 7) << 4;

  auto stageK = [&](int buf, int s0) {
    #pragma unroll
    for (int it = 0; it < 4; ++it) {
      int o = it*8192 + tid*16;                 // 512 threads x 16B x 4
      int row = o >> 10, cb = o & 1023;
      int cbs = cb ^ ((row & 7) << 4);
      glds16(kBase + (size_t)(s0 + row)*512 + (cbs >> 1),
             (char*)Ks[buf] + it*8192 + ((tid >> 6) << 10));
    }
  };
  auto stageV = [&](int buf, int s0) {
    #pragma unroll
    for (int it = 0; it < 4; ++it) {
      int F = it*8192 + tid*16;                 // flat LDS byte offset
      int d = F >> 6;                           // V row (0..511)
      int cl = (F & 63) ^ (((d >> 1) & 3) << 4);
      glds16(vBase + (size_t)d*1024 + s0 + (cl >> 1),
             (char*)Vs[buf] + it*8192 + ((tid >> 6) << 10));
    }
  };

  stageK(0, 0);
  stageV(0, 0);
  __syncthreads();

  for (int itr = 0; itr < 32; ++itr) {
    const int s0 = itr << 5;
    const int cur = itr & 1;
    if (itr < 31) { stageK(cur ^ 1, s0 + 32); stageV(cur ^ 1, s0 + 32); }

    // ---- QK^T from LDS
    f32x4 sf0 = f32x4{0.f,0.f,0.f,0.f};
    f32x4 sf1 = f32x4{0.f,0.f,0.f,0.f};
    const char* ksb = (const char*)Ks[cur];
    #pragma unroll
    for (int ks = 0; ks < 16; ++ks) {
      int col = (ks*64 + l4*16) ^ kswz;
      s16x8 k0 = *(const s16x8*)(ksb + l15*1024 + col);
      s16x8 k1 = *(const s16x8*)(ksb + (16 + l15)*1024 + col);
      sf0 = mfma16(k0, qf[ks], sf0);
      sf1 = mfma16(k1, qf[ks], sf1);
    }
    u16x4 p0, p1;
    #pragma unroll
    for (int r = 0; r < 4; ++r) {
      float e0 = exp2f(sf0[r] * c1);
      float e1 = exp2f(sf1[r] * c1);
      L += e0 + e1;
      p0[r] = f2bf(e0);
      p1[r] = f2bf(e1);
    }
    // P round-trip is wave-private (no barrier needed)
    *(u16x4*)(myP + l15*64 + (( l4*8      ) ^ swz)) = p0;
    *(u16x4*)(myP + l15*64 + ((32 + l4*8  ) ^ swz)) = p1;
    s16x8 pb = *(const s16x8*)(myP + l15*64 + ((l4*16) ^ swz));

    // ---- PV from LDS (swizzled packed rows)
    const char* vsb = (const char*)Vs[cur];
    #pragma unroll
    for (int df = 0; df < 32; ++df) {
      int d = df*16 + l15;
      int off = (d << 6) + ((l4 << 4) ^ (((d >> 1) & 3) << 4));
      s16x8 va = *(const s16x8*)(vsb + off);
      z[df] = mfma16(va, pb, z[df]);
    }
    __syncthreads();   // next-tile stage drained; cur safe to restage next iter
  }

  // rowsum over the four lane-groups
  L += __shfl_xor(L, 16);
  L += __shfl_xor(L, 32);
  float inv = 1.f / L;

  float s1 = 0.f, s2 = 0.f;
  #pragma unroll
  for (int df = 0; df < 32; ++df)
    #pragma unroll
    for (int r = 0; r < 4; ++r) {
      float v = z[df][r] * inv;
      z[df][r] = v;
      s1 += v; s2 += v*v;
    }
  s1 += __shfl_xor(s1, 16); s1 += __shfl_xor(s1, 32);
  s2 += __shfl_xor(s2, 16); s2 += __shfl_xor(s2, 32);
  const float mean = s1 * (1.f/512.f);
  const float var  = s2 * (1.f/512.f) - mean*mean;
  const float rstd = rsqrtf(var + 1e-5f);

  const float* gp = lng + h*512;
  const float* bp = lnb + h*512;
  u16* zp = zO + ((size_t)(b*1024 + t0 + l15))*4096 + h*512;
  #pragma unroll
  for (int df = 0; df < 32; ++df) {
    int d0 = df*16 + l4*4;
    float4 gv  = *(const float4*)(gp + d0);
    float4 bbv = *(const float4*)(bp + d0);
    u16x4 pk;
    pk[0] = f2bf((z[df][0]-mean)*rstd*gv.x + bbv.x);
    pk[1] = f2bf((z[df][1]-mean)*rstd*gv.y + bbv.y);
    pk[2] = f2bf((z[df][2]-mean)*rstd*gv.z + bbv.z);
    pk[3] = f2bf((z[df][3]-mean)*rstd*gv.w + bbv.w);
    *(u16x4*)(zp + d0) = pk;
  }
}

// ---------------------------------------------------------------- final FC
// out = zc @ Wf + bf + x ;  A = zb [8192,4096], B = wft [512][4096]
__global__ __launch_bounds__(256, 2) void gemm_fc(
    const u16* __restrict__ zb, const u16* __restrict__ wft,
    const float* __restrict__ bf_, const float* __restrict__ x,
    float* __restrict__ out)
{
  __shared__ u16 As[128*64];
  __shared__ u16 Bs[128*64];
  const int tid = threadIdx.x;
  const int lane = tid & 63, w = tid >> 6;
  const int wm = w >> 1, wn = w & 1;
  const int l15 = lane & 15, l4 = lane >> 4;
  const int mt = blockIdx.x >> 2, nt = blockIdx.x & 3;
  const int m0 = mt * 128, n0 = nt * 128;

  const u16* aSrc = zb + (size_t)m0 * 4096;
  const u16* bSrc = wft + (size_t)n0 * 4096;

  f32x4 acc[4][4];
  #pragma unroll
  for (int i = 0; i < 4; ++i)
    #pragma unroll
    for (int j = 0; j < 4; ++j) acc[i][j] = f32x4{0.f,0.f,0.f,0.f};

  for (int kt = 0; kt < 64; ++kt) {
    const int kofs = kt * 64;
    STAGE_TILE(aSrc, 4096, As);
    STAGE_TILE(bSrc, 4096, Bs);
    __syncthreads();
    #pragma unroll
    for (int kk = 0; kk < 2; ++kk) {
      s16x8 af[4], bfr[4];
      #pragma unroll
      for (int i = 0; i < 4; ++i) {
        int rowA = wm*64 + i*16 + l15;
        af[i] = *(const s16x8*)((const char*)As + rowA*128 + ((kk*64 + l4*16) ^ ((rowA & 7) << 4)));
        int rowB = wn*64 + i*16 + l15;
        bfr[i] = *(const s16x8*)((const char*)Bs + rowB*128 + ((kk*64 + l4*16) ^ ((rowB & 7) << 4)));
      }
      #pragma unroll
      for (int i = 0; i < 4; ++i)
        #pragma unroll
        for (int j = 0; j < 4; ++j)
          acc[i][j] = mfma16(af[i], bfr[j], acc[i][j]);
    }
    __syncthreads();
  }

  const int dBase = n0 + wn*64;
  const int mBase = m0 + wm*64;
  #pragma unroll
  for (int j = 0; j < 4; ++j) {
    int d = dBase + j*16 + l15;
    float bvs = bf_[d];
    #pragma unroll
    for (int i = 0; i < 4; ++i) {
      int m = mBase + i*16 + l4*4;
      #pragma unroll
      for (int r = 0; r < 4; ++r) {
        size_t idx = (size_t)(m + r)*512 + d;
        out[idx] = acc[i][j][r] + bvs + x[idx];
      }
    }
  }
}

// ------------------------------------------------------------------ launch
extern "C" void kernel_launch(void* const* d_in, const int* in_sizes, int n_in,
                              void* d_out, int out_size, void* d_ws, size_t ws_size,
                              hipStream_t stream) {
  const float* x   = (const float*)d_in[0];
  const float* Wq  = (const float*)d_in[1];
  const float* bq  = (const float*)d_in[2];
  const float* Wk  = (const float*)d_in[3];
  const float* bk  = (const float*)d_in[4];
  const float* Wv  = (const float*)d_in[5];
  const float* bv  = (const float*)d_in[6];
  const float* lng = (const float*)d_in[7];
  const float* lnb = (const float*)d_in[8];
  const float* Wf  = (const float*)d_in[9];
  const float* bf_ = (const float*)d_in[10];
  float* out = (float*)d_out;

  // ws layout (bytes):
  //   xbf  [8192][512] bf16                  @ 0          (8,388,608)
  //   wt   [24][512][512] bf16               @ 8,388,608  (12,582,912)
  //   wft  [512][4096] bf16                  @ 20,971,520 (4,194,304)
  //   zb   [8192][4096] bf16                 @ 25,165,824 (67,108,864)
  //   q,k,v: g heads each, 8,388,608*g each  @ 92,274,688
  // peak = 92,274,688 + 3*g*8,388,608 : g=8 -> 280 MiB, 4 -> 184, 2 -> 136, 1 -> 112.
  char* ws = (char*)d_ws;
  u16* xbf = (u16*)(ws);
  u16* wt  = (u16*)(ws + 8388608);
  u16* wft = (u16*)(ws + 20971520);
  u16* zb  = (u16*)(ws + 25165824);

  const size_t headB = 8388608;  // one head of q/k/v in bytes
  const size_t base  = 92274688;
  int g, lg;
  if      (ws_size >= base + 24*headB) { g = 8; lg = 3; }
  else if (ws_size >= base + 12*headB) { g = 4; lg = 2; }
  else if (ws_size >= base +  6*headB) { g = 2; lg = 1; }
  else                                 { g = 1; lg = 0; }

  u16* qb = (u16*)(ws + base);
  u16* kb = (u16*)(ws + base + (size_t)g*headB);
  u16* vt = (u16*)(ws + base + (size_t)2*g*headB);

  cvt_x<<<2048, 256, 0, stream>>>(x, xbf, 524288);
  dim3 tb(32, 8);
  transpose_f32_to_bf16<<<dim3(256, 8), tb, 0, stream>>>(Wq, wt,             512, 512, 262144, 262144);
  transpose_f32_to_bf16<<<dim3(256, 8), tb, 0, stream>>>(Wk, wt +  8*262144, 512, 512, 262144, 262144);
  transpose_f32_to_bf16<<<dim3(256, 8), tb, 0, stream>>>(Wv, wt + 16*262144, 512, 512, 262144, 262144);
  transpose_f32_to_bf16<<<dim3(2048, 1), tb, 0, stream>>>(Wf, wft, 4096, 512, 0, 0);

  for (int h0 = 0; h0 < H_; h0 += g) {
    gemm_qkv<<<dim3(256, 3*g), 256, 0, stream>>>(xbf, wt, bq, bk, bv, qb, kb, vt, h0, lg);
    attn<<<dim3(64*g), 512, 0, stream>>>(qb, kb, vt, lng, lnb, zb, h0);
  }
  gemm_fc<<<256, 256, 0, stream>>>(zb, wft, bf_, x, out);
}